// Round 2
// baseline (273.081 us; speedup 1.0000x reference)
//
#include <hip/hip_runtime.h>
#include <math.h>

#define N_ROWS 65536
#define KCODES 8192
#define DIM 64
#define MARGIN 2.0e-3f          // f16 single-term bound (~1e-3) + 2x 11-bit packing trunc (4.9e-4) + slack
#define KSPLIT 4
#define KPER (KCODES / KSPLIT)   // 2048
#define NROUNDS (KPER / 128)     // 16 rounds of 128 codes
#define LIST_CAP 16384
#define FB_ROWS 16

// ws layout (floats) — proven footprint (606209 floats)
#define WS_WSQ   0          // 8192
#define WS_IDX   8192       // 65536 ints
#define WS_BINS  73728      // 8192
#define WS_ESUM  81920      // 524288  (wT during fallback; esum memset after fallback)
#define WS_LOSS  606208     // 1

// d_out scratch map (all regions rewritten by later kernels):
//   zn fp32:   out[0 .. 4194304)           (z_q region; stats overwrites with z_q)
//   count:     out[4194304]                (out_loss slot; finalize overwrites)
//   list:      out[4194305 .. 4259841)     (out_idx region; stats overwrites)
//   wh f16:    out[4268032 .. 4530176)     (ea region; finalize overwrites)
//   pm1:       out[4792321 .. 5054465)     (out_w region; finalize overwrites)
//   pack:      out[5054465 .. 5316609)
//   fb64 u64:  out[4792322 .. 5054466)     (8B-aligned; reuses pm1/pack region after merge)

typedef _Float16 half8 __attribute__((ext_vector_type(8)));
typedef float f32x4 __attribute__((ext_vector_type(4)));

#define MFMA_F16(A, B, C) __builtin_amdgcn_mfma_f32_16x16x32_f16(A, B, C, 0, 0, 0)

__device__ __forceinline__ void gload16(const unsigned short* g, unsigned short* l) {
    __builtin_amdgcn_global_load_lds(
        (const __attribute__((address_space(1))) unsigned int*)g,
        (__attribute__((address_space(3))) unsigned int*)l, 16, 0, 0);
}

// ---------------- kernel A (fused): normalize z | per-code norms + f16 plane + zero bins | transpose w ----------------
#define NZB 1024                 // prep_z blocks
#define NWB 2048                 // prep_w blocks
#define NTB 128                  // prep_wT blocks
__global__ void prep_kernel(const float* __restrict__ z, const float* __restrict__ w,
                            float* __restrict__ zn, float* __restrict__ wsq,
                            unsigned short* __restrict__ wh, float* __restrict__ wT,
                            float* __restrict__ bins, int* __restrict__ countp,
                            float* __restrict__ loss) {
    __shared__ float tile[64 * 65];
    const int bid = blockIdx.x;
    const int t = threadIdx.x;
    const int lane = t & 63;
    const int wv = t >> 6;

    if (bid < NZB) {
        const int base = bid * 64;
        for (int i = 0; i < 16; ++i) {
            int row = base + i * 4 + wv;
            float v = z[(size_t)row * DIM + lane];
            float s = v * v;
            #pragma unroll
            for (int off = 32; off > 0; off >>= 1) s += __shfl_xor(s, off);
            zn[(size_t)row * DIM + lane] = v / fmaxf(sqrtf(s), 1e-12f);
        }
    } else if (bid < NZB + NWB) {
        if (bid == NZB && t == 0) { *countp = 0; *loss = 0.f; }
        int wid = (bid - NZB) * 4 + wv;
        float v = w[(size_t)wid * DIM + lane];
        float s = v * v;
        #pragma unroll
        for (int off = 32; off > 0; off >>= 1) s += __shfl_xor(s, off);
        if (lane == 0) { wsq[wid] = s; bins[wid] = 0.f; }
        _Float16 h = (_Float16)v;
        wh[(size_t)wid * 64 + lane] = __builtin_bit_cast(unsigned short, h);
    } else {
        const int c0 = (bid - NZB - NWB) * 64;
        #pragma unroll
        for (int i = 0; i < 16; ++i) {
            int idx = i * 256 + t;
            int c = idx >> 6, d = idx & 63;
            tile[c * 65 + d] = w[(size_t)(c0 + c) * DIM + d];
        }
        __syncthreads();
        #pragma unroll
        for (int i = 0; i < 16; ++i) {
            int idx = i * 256 + t;
            int d = idx >> 6, c = idx & 63;
            wT[(size_t)d * KCODES + c0 + c] = tile[c * 65 + d];
        }
    }
}

// ---------------- kernel B: K-split MFMA argmax-dot, fp16 single-term, packed value+index ----------------
// acc bias C=1.0 -> values in [0,2] (positive => float order == uint order); low 11 mantissa
// bits carry the partition-local code. Top-2 tracking: and_or + med3 + max per dot.
__launch_bounds__(256, 5)
__global__ void argmin_mfma_kernel(const float* __restrict__ zn,
                                   const unsigned short* __restrict__ wh,
                                   float* __restrict__ pm1,
                                   unsigned int* __restrict__ pack) {
    __shared__ unsigned short smem[16384];   // 2 x (128 codes x 64 halves) = 2 x 16KB

    const int tid = threadIdx.x;
    const int lane = tid & 63;
    const int wv = tid >> 6;
    const int n_a = lane & 15;
    const int quad = lane >> 4;
    const int rowblk = blockIdx.x >> 2;
    const int kq = blockIdx.x & 3;
    const int kbase = kq * KPER;

    // stage 128 codes x 64 halves = 16KB, XOR-swizzled (chunk j of code c at slot j^(c&7))
    #define ISSUE_TILE(r, bdst)                                                  \
        {                                                                        \
            const size_t cg0 = (size_t)(kbase + (r) * 128);                      \
            _Pragma("unroll")                                                    \
            for (int i = 0; i < 4; ++i) {                                        \
                int slot = wv * 256 + i * 64 + lane;                             \
                int cl = slot >> 3;                                              \
                int jg = (slot & 7) ^ (cl & 7);                                  \
                gload16(wh + (cg0 + cl) * 64 + jg * 8,                           \
                        (bdst) + wv * 2048 + i * 512);                           \
            }                                                                    \
        }

    ISSUE_TILE(0, smem);

    half8 a_h[2][2];
    #pragma unroll
    for (int mt = 0; mt < 2; ++mt) {
        int row = rowblk * 128 + wv * 32 + mt * 16 + n_a;
        #pragma unroll
        for (int ks = 0; ks < 2; ++ks) {
            const float* p = zn + (size_t)row * DIM + ks * 32 + quad * 8;
            float4 f0 = *(const float4*)p;
            float4 f1 = *(const float4*)(p + 4);
            float f[8] = {f0.x, f0.y, f0.z, f0.w, f1.x, f1.y, f1.z, f1.w};
            half8 vh;
            #pragma unroll
            for (int j = 0; j < 8; ++j) vh[j] = (_Float16)f[j];   // RTNE
            a_h[mt][ks] = vh;
        }
    }

    float m1v[2][4], m2v[2][4];
    #pragma unroll
    for (int mt = 0; mt < 2; ++mt)
        #pragma unroll
        for (int i = 0; i < 4; ++i) { m1v[mt][i] = 0.f; m2v[mt][i] = 0.f; }

    __syncthreads();

    for (int r = 0; r < NROUNDS; ++r) {
        unsigned short* bc = smem + (r & 1) * 8192;
        if (r + 1 < NROUNDS) ISSUE_TILE(r + 1, smem + ((r + 1) & 1) * 8192);
        const int rbase = r * 128;

        #pragma unroll
        for (int nt = 0; nt < 8; ++nt) {
            const int cl = nt * 16 + n_a;
            const unsigned short* bp = bc + cl * 64;
            half8 b0 = *(const half8*)(bp + ((quad ^ (n_a & 7)) * 8));
            half8 b1 = *(const half8*)(bp + (((4 + quad) ^ (n_a & 7)) * 8));
            const unsigned c = (unsigned)(rbase + nt * 16 + n_a);   // 11-bit local code
            #pragma unroll
            for (int mt = 0; mt < 2; ++mt) {
                f32x4 a = {1.f, 1.f, 1.f, 1.f};   // +1 bias keeps values positive
                a = MFMA_F16(a_h[mt][0], b0, a);
                a = MFMA_F16(a_h[mt][1], b1, a);
                #pragma unroll
                for (int i = 0; i < 4; ++i) {
                    float pk = __uint_as_float((__float_as_uint(a[i]) & 0xFFFFF800u) | c);
                    m2v[mt][i] = __builtin_amdgcn_fmed3f(pk, m1v[mt][i], m2v[mt][i]);
                    m1v[mt][i] = fmaxf(m1v[mt][i], pk);
                }
            }
        }
        __syncthreads();
    }

    #pragma unroll
    for (int mt = 0; mt < 2; ++mt)
        #pragma unroll
        for (int i = 0; i < 4; ++i) {
            float v1 = m1v[mt][i], v2 = m2v[mt][i];
            #pragma unroll
            for (int off = 1; off < 16; off <<= 1) {
                float o1 = __shfl_xor(v1, off);
                float o2 = __shfl_xor(v2, off);
                float lo = fminf(v1, o1);
                v2 = fmaxf(fmaxf(v2, o2), lo);
                v1 = fmaxf(v1, o1);
            }
            if (n_a == 0) {
                int row_g = rowblk * 128 + wv * 32 + mt * 16 + quad * 4 + i;
                pm1[row_g * 4 + kq] = v1;
                pack[row_g * 4 + kq] = __float_as_uint(v2);
            }
        }
    #undef ISSUE_TILE
}

// ---------------- kernel C: merge 4 K-partials per row, flag close rows ----------------
__global__ void merge_kernel(const float* __restrict__ pm1, const unsigned int* __restrict__ pack,
                             int* __restrict__ idx_ws,
                             int* __restrict__ countp, int* __restrict__ list) {
    int row = blockIdx.x * blockDim.x + threadIdx.x;
    if (row >= N_ROWS) return;
    float v1 = -3.4e38f, v2 = -3.4e38f;
    int bq = 0;
    #pragma unroll
    for (int kq = 0; kq < KSPLIT; ++kq) {
        float a1 = pm1[row * 4 + kq];
        float a2 = __uint_as_float(pack[row * 4 + kq]);
        if (a1 > v1) { v2 = fmaxf(v1, a2); v1 = a1; bq = kq; }
        else { v2 = fmaxf(v2, a1); }
    }
    idx_ws[row] = (int)(__float_as_uint(v1) & 0x7FFu) + bq * KPER;
    float vt1 = __uint_as_float(__float_as_uint(v1) & 0xFFFFF800u);
    float vt2 = __uint_as_float(__float_as_uint(v2) & 0xFFFFF800u);
    if (vt1 - vt2 < MARGIN) {
        int pos = atomicAdd(countp, 1);
        if (pos < LIST_CAP) list[pos] = row;
    }
}

// ---------------- kernel D: exact fp32 re-rank, batched 16 rows x 1024-code chunk ----------------
// unit = (group of 16 flagged rows, chunk of 1024 codes): wT read once per 16 rows.
// Result packed u64 = (ordered(dist) << 13) | code  ->  min == (smallest dist, then smallest k).
__launch_bounds__(256, 4)
__global__ void fallback_kernel(const float* __restrict__ zn, const float* __restrict__ wT,
                                const float* __restrict__ wsq,
                                const int* __restrict__ countp, const int* __restrict__ list,
                                unsigned long long* __restrict__ fb64) {
    __shared__ float zr_s[FB_ROWS][64];
    __shared__ unsigned long long red_s[FB_ROWS][4];

    const int t = threadIdx.x;
    const int lane = t & 63;
    const int wv = t >> 6;
    const int count = min(*countp, LIST_CAP);
    const int ngroups = (count + FB_ROWS - 1) / FB_ROWS;
    const int nunits = ngroups * 8;

    for (int bi = blockIdx.x; bi < nunits; bi += gridDim.x) {
        const int g = bi >> 3;
        const int chunk = bi & 7;

        __syncthreads();   // protect LDS reuse across grid-stride iterations
        for (int i = t; i < FB_ROWS * 64; i += 256) {
            int rl = i >> 6, d = i & 63;
            int slot = g * FB_ROWS + rl;
            int row = list[slot < count ? slot : (count - 1)];
            zr_s[rl][d] = zn[(size_t)row * DIM + d];
        }
        __syncthreads();

        const int c0 = chunk * 1024 + t;
        float acc[4][FB_ROWS];
        #pragma unroll
        for (int j = 0; j < 4; ++j)
            #pragma unroll
            for (int rr = 0; rr < FB_ROWS; ++rr) acc[j][rr] = 0.f;

        const float* wTp = wT + c0;
        #pragma unroll 2
        for (int d = 0; d < 64; ++d) {
            const float* p = wTp + (size_t)d * KCODES;
            float w0 = p[0], w1 = p[256], w2 = p[512], w3 = p[768];
            #pragma unroll
            for (int rr = 0; rr < FB_ROWS; ++rr) {
                float zd = zr_s[rr][d];
                acc[0][rr] = fmaf(zd, w0, acc[0][rr]);
                acc[1][rr] = fmaf(zd, w1, acc[1][rr]);
                acc[2][rr] = fmaf(zd, w2, acc[2][rr]);
                acc[3][rr] = fmaf(zd, w3, acc[3][rr]);
            }
        }
        float q0 = wsq[c0], q1 = wsq[c0 + 256], q2 = wsq[c0 + 512], q3 = wsq[c0 + 768];

        #pragma unroll
        for (int rr = 0; rr < FB_ROWS; ++rr) {
            float dj[4] = {q0 - 2.f * acc[0][rr], q1 - 2.f * acc[1][rr],
                           q2 - 2.f * acc[2][rr], q3 - 2.f * acc[3][rr]};
            unsigned long long best = 0xFFFFFFFFFFFFFFFFull;
            #pragma unroll
            for (int j = 0; j < 4; ++j) {
                int s = __float_as_int(dj[j]);
                unsigned o = (unsigned)s ^ (unsigned)((s >> 31) | (int)0x80000000);
                unsigned long long pk = ((unsigned long long)o << 13) | (unsigned)(c0 + j * 256);
                best = pk < best ? pk : best;
            }
            #pragma unroll
            for (int off = 1; off < 64; off <<= 1) {
                unsigned lo = __shfl_xor((unsigned)(best & 0xffffffffu), off);
                unsigned hi = __shfl_xor((unsigned)(best >> 32), off);
                unsigned long long ob = ((unsigned long long)hi << 32) | lo;
                best = ob < best ? ob : best;
            }
            if (lane == 0) red_s[rr][wv] = best;
        }
        __syncthreads();
        if (t < FB_ROWS) {
            unsigned long long best = red_s[t][0];
            #pragma unroll
            for (int i2 = 1; i2 < 4; ++i2) best = red_s[t][i2] < best ? red_s[t][i2] : best;
            int slot = g * FB_ROWS + t;
            if (slot < count) fb64[(size_t)slot * 8 + chunk] = best;
        }
    }
}

// ---------------- kernel D2: merge 8 chunk partials per flagged row ----------------
__global__ void merge2_kernel(const unsigned long long* __restrict__ fb64,
                              const int* __restrict__ countp, const int* __restrict__ list,
                              int* __restrict__ idx_ws) {
    int slot = blockIdx.x * blockDim.x + threadIdx.x;
    int count = min(*countp, LIST_CAP);
    if (slot >= count) return;
    unsigned long long best = fb64[(size_t)slot * 8];
    #pragma unroll
    for (int c = 1; c < 8; ++c) {
        unsigned long long v = fb64[(size_t)slot * 8 + c];
        best = v < best ? v : best;
    }
    idx_ws[list[slot]] = (int)(best & 0x1FFFull);
}

// ---------------- kernel E: gather z_q (over zn in-place), idx out, loss, EMA scatter ----------------
__global__ void stats_kernel(float* __restrict__ zq,              // holds zn on entry
                             const float* __restrict__ w,
                             const int* __restrict__ idx_ws,
                             float* __restrict__ idx_out,
                             float* __restrict__ bins,
                             float* __restrict__ esum,
                             float* __restrict__ loss_acc) {
    const int lane = threadIdx.x & 63;
    const int wv = threadIdx.x >> 6;
    const int gw = blockIdx.x * 4 + wv;
    const int nw = gridDim.x * 4;
    float lsum = 0.f;
    for (int row = gw; row < N_ROWS; row += nw) {
        float znv = zq[(size_t)row * DIM + lane];
        int k = idx_ws[row];
        float wq = w[(size_t)k * DIM + lane];
        zq[(size_t)row * DIM + lane] = wq;
        if (lane == 0) idx_out[row] = (float)k;
        float diff = wq - znv;
        lsum += diff * diff;
        atomicAdd(&esum[(size_t)k * DIM + lane], znv);
        if (lane == 0) atomicAdd(&bins[k], 1.0f);
    }
    __shared__ float red[256];
    red[threadIdx.x] = lsum;
    __syncthreads();
    for (int s = 128; s > 0; s >>= 1) {
        if (threadIdx.x < s) red[threadIdx.x] += red[threadIdx.x + s];
        __syncthreads();
    }
    if (threadIdx.x == 0) atomicAdd(loss_acc, red[0]);
}

// ---------------- kernel F: per-code EMA finalize + loss scalar ----------------
__global__ void finalize_kernel(const float* __restrict__ w,
                                const float* __restrict__ cs,
                                const float* __restrict__ ea,
                                const float* __restrict__ bins,
                                const float* __restrict__ esum,
                                const float* __restrict__ loss_acc,
                                float* __restrict__ out_cs,
                                float* __restrict__ out_ea,
                                float* __restrict__ out_w,
                                float* __restrict__ out_loss) {
    const int gid = blockIdx.x * blockDim.x + threadIdx.x;
    if (gid == 0) out_loss[0] = 0.25f * loss_acc[0] / 4194304.0f;
    const int k = gid >> 6;
    const int lane = threadIdx.x & 63;
    if (k >= KCODES) return;
    float b = bins[k];
    if (lane == 0) out_cs[k] = cs[k] * 0.99f + 0.01f * b;
    size_t off = (size_t)k * DIM + lane;
    float es = esum[off];
    out_ea[off] = ea[off] * 0.99f + 0.01f * es;
    float wv = w[off];
    float bc = (b == 0.0f) ? 1.0f : b;
    float t = es / bc;
    float s = t * t;
    #pragma unroll
    for (int o = 32; o > 0; o >>= 1) s += __shfl_xor(s, o);
    float en = t / fmaxf(sqrtf(s), 1e-12f);
    if (b == 0.0f) en = wv;
    float nw = wv * 0.99f + 0.01f * en;
    float s2 = nw * nw;
    #pragma unroll
    for (int o = 32; o > 0; o >>= 1) s2 += __shfl_xor(s2, o);
    out_w[off] = nw / fmaxf(sqrtf(s2), 1e-12f);
}

extern "C" void kernel_launch(void* const* d_in, const int* in_sizes, int n_in,
                              void* d_out, int out_size, void* d_ws, size_t ws_size,
                              hipStream_t stream) {
    const float* z  = (const float*)d_in[0];
    const float* w  = (const float*)d_in[1];
    const float* cs = (const float*)d_in[2];
    const float* ea = (const float*)d_in[3];

    float* out = (float*)d_out;
    float* out_zq   = out;                 // 4194304  (zn scratch)
    float* out_loss = out + 4194304;       // 1        (count scratch)
    float* out_idx  = out + 4194305;       // 65536    (list scratch)
    float* out_cs   = out + 4259841;       // 8192
    float* out_ea   = out + 4268033;       // 524288
    float* out_w    = out + 4792321;       // 524288   (pm1/fb64 + pack scratch)

    float*              zn     = out_zq;
    int*                countp = (int*)(out + 4194304);
    int*                list   = (int*)(out + 4194305);
    unsigned short*     wh     = (unsigned short*)(out + 4268032);   // 16B-aligned, 1MB
    float*              pm1    = out + 4792321;
    unsigned int*       pack   = (unsigned int*)(out + 5054465);
    unsigned long long* fb64   = (unsigned long long*)(out + 4792322); // 8B-aligned, 1MB

    float* ws = (float*)d_ws;
    float* wsq  = ws + WS_WSQ;
    int*   idxb = (int*)(ws + WS_IDX);
    float* bins = ws + WS_BINS;
    float* esum = ws + WS_ESUM;
    float* wT   = ws + WS_ESUM;            // wT lives here until esum memset
    float* loss = ws + WS_LOSS;

    prep_kernel<<<NZB + NWB + NTB, 256, 0, stream>>>(z, w, zn, wsq, wh, wT, bins, countp, loss);
    argmin_mfma_kernel<<<(N_ROWS / 128) * KSPLIT, 256, 0, stream>>>(zn, wh, pm1, pack);
    merge_kernel<<<N_ROWS / 256, 256, 0, stream>>>(pm1, pack, idxb, countp, list);
    fallback_kernel<<<2048, 256, 0, stream>>>(zn, wT, wsq, countp, list, fb64);
    merge2_kernel<<<LIST_CAP / 256, 256, 0, stream>>>(fb64, countp, list, idxb);
    // wT no longer needed; zero esum (same region) for the scatter
    hipMemsetAsync(esum, 0, (size_t)524288 * sizeof(float), stream);
    stats_kernel<<<512, 256, 0, stream>>>(out_zq, w, idxb, out_idx, bins, esum, loss);
    finalize_kernel<<<KCODES * 64 / 256, 256, 0, stream>>>(w, cs, ea, bins, esum, loss,
                                                           out_cs, out_ea, out_w, out_loss);
}

// Round 3
// 239.925 us; speedup vs baseline: 1.1382x; 1.1382x over previous
//
#include <hip/hip_runtime.h>
#include <math.h>

#define N_ROWS 65536
#define KCODES 8192
#define DIM 64
#define MARGIN 1.3e-3f          // 11-bit pack trunc (2.44e-4) + 2x15sigma f16 dot err
#define KSPLIT 4
#define KPER (KCODES / KSPLIT)   // 2048
#define NROUNDS (KPER / 128)     // 16 rounds of 128 codes
#define LIST_CAP 16384
#define FB_ROWS 16

// ws layout (floats) — proven footprint (606209 floats)
#define WS_WSQ   0          // 8192
#define WS_IDX   8192       // 65536 ints
#define WS_BINS  73728      // 8192
#define WS_ESUM  81920      // 524288  (wT during fallback; esum zeroed in merge2)
#define WS_LOSS  606208     // 1

// d_out scratch map (all regions rewritten by later kernels):
//   zn fp32:   out[0 .. 4194304)           (z_q region; stats overwrites with z_q)
//   lists u32: out[4194305 .. 4259841)     (out_idx region; 4 x 16384; stats overwrites)
//   countk:    out[4259841 .. 4259845)     (out_cs region; finalize overwrites)
//   wh f16:    out[4268032 .. 4530176)     (ea region first half; finalize overwrites)
//   fbcell u64:out[4530178 .. 4661250)     (ea region second half; finalize overwrites)
//   pm1:       out[4792321 .. 5054465)     (out_w region; finalize overwrites)
//   pack:      out[5054465 .. 5316609)

typedef _Float16 half8 __attribute__((ext_vector_type(8)));
typedef float f32x4 __attribute__((ext_vector_type(4)));

#define MFMA_F16(A, B, C) __builtin_amdgcn_mfma_f32_16x16x32_f16(A, B, C, 0, 0, 0)

__device__ __forceinline__ void gload16(const unsigned short* g, unsigned short* l) {
    __builtin_amdgcn_global_load_lds(
        (const __attribute__((address_space(1))) unsigned int*)g,
        (__attribute__((address_space(3))) unsigned int*)l, 16, 0, 0);
}

// ---------------- kernel A (fused): normalize z | w norms + f16 plane + zero bins | transpose w ----------------
#define NZB 1024                 // prep_z blocks (also init fbcell)
#define NWB 2048                 // prep_w blocks
#define NTB 128                  // prep_wT blocks
__global__ void prep_kernel(const float* __restrict__ z, const float* __restrict__ w,
                            float* __restrict__ zn, float* __restrict__ wsq,
                            unsigned short* __restrict__ wh, float* __restrict__ wT,
                            float* __restrict__ bins, int* __restrict__ countk,
                            unsigned long long* __restrict__ fbcell,
                            float* __restrict__ loss) {
    __shared__ float tile[64 * 65];
    const int bid = blockIdx.x;
    const int t = threadIdx.x;
    const int lane = t & 63;
    const int wv = t >> 6;

    if (bid < NZB) {
        if (t < 64) fbcell[bid * 64 + t] = ~0ull;    // init all row cells
        const int base = bid * 64;
        for (int i = 0; i < 16; ++i) {
            int row = base + i * 4 + wv;
            float v = z[(size_t)row * DIM + lane];
            float s = v * v;
            #pragma unroll
            for (int off = 32; off > 0; off >>= 1) s += __shfl_xor(s, off);
            zn[(size_t)row * DIM + lane] = v / fmaxf(sqrtf(s), 1e-12f);
        }
    } else if (bid < NZB + NWB) {
        if (bid == NZB) {
            if (t < 4) countk[t] = 0;
            if (t == 4) *loss = 0.f;
        }
        int wid = (bid - NZB) * 4 + wv;
        float v = w[(size_t)wid * DIM + lane];
        float s = v * v;
        #pragma unroll
        for (int off = 32; off > 0; off >>= 1) s += __shfl_xor(s, off);
        if (lane == 0) { wsq[wid] = s; bins[wid] = 0.f; }
        _Float16 h = (_Float16)v;
        wh[(size_t)wid * 64 + lane] = __builtin_bit_cast(unsigned short, h);
    } else {
        const int c0 = (bid - NZB - NWB) * 64;
        #pragma unroll
        for (int i = 0; i < 16; ++i) {
            int idx = i * 256 + t;
            int c = idx >> 6, d = idx & 63;
            tile[c * 65 + d] = w[(size_t)(c0 + c) * DIM + d];
        }
        __syncthreads();
        #pragma unroll
        for (int i = 0; i < 16; ++i) {
            int idx = i * 256 + t;
            int d = idx >> 6, c = idx & 63;
            wT[(size_t)d * KCODES + c0 + c] = tile[c * 65 + d];
        }
    }
}

// ---------------- kernel B: K-split MFMA argmax-dot, fp16 single-term, packed value+index ----------------
__launch_bounds__(256, 5)
__global__ void argmin_mfma_kernel(const float* __restrict__ zn,
                                   const unsigned short* __restrict__ wh,
                                   float* __restrict__ pm1,
                                   unsigned int* __restrict__ pack) {
    __shared__ unsigned short smem[16384];   // 2 x (128 codes x 64 halves) = 2 x 16KB

    const int tid = threadIdx.x;
    const int lane = tid & 63;
    const int wv = tid >> 6;
    const int n_a = lane & 15;
    const int quad = lane >> 4;
    const int rowblk = blockIdx.x >> 2;
    const int kq = blockIdx.x & 3;
    const int kbase = kq * KPER;

    #define ISSUE_TILE(r, bdst)                                                  \
        {                                                                        \
            const size_t cg0 = (size_t)(kbase + (r) * 128);                      \
            _Pragma("unroll")                                                    \
            for (int i = 0; i < 4; ++i) {                                        \
                int slot = wv * 256 + i * 64 + lane;                             \
                int cl = slot >> 3;                                              \
                int jg = (slot & 7) ^ (cl & 7);                                  \
                gload16(wh + (cg0 + cl) * 64 + jg * 8,                           \
                        (bdst) + wv * 2048 + i * 512);                           \
            }                                                                    \
        }

    ISSUE_TILE(0, smem);

    half8 a_h[2][2];
    #pragma unroll
    for (int mt = 0; mt < 2; ++mt) {
        int row = rowblk * 128 + wv * 32 + mt * 16 + n_a;
        #pragma unroll
        for (int ks = 0; ks < 2; ++ks) {
            const float* p = zn + (size_t)row * DIM + ks * 32 + quad * 8;
            float4 f0 = *(const float4*)p;
            float4 f1 = *(const float4*)(p + 4);
            float f[8] = {f0.x, f0.y, f0.z, f0.w, f1.x, f1.y, f1.z, f1.w};
            half8 vh;
            #pragma unroll
            for (int j = 0; j < 8; ++j) vh[j] = (_Float16)f[j];   // RTNE
            a_h[mt][ks] = vh;
        }
    }

    float m1v[2][4], m2v[2][4];
    #pragma unroll
    for (int mt = 0; mt < 2; ++mt)
        #pragma unroll
        for (int i = 0; i < 4; ++i) { m1v[mt][i] = 0.f; m2v[mt][i] = 0.f; }

    __syncthreads();

    for (int r = 0; r < NROUNDS; ++r) {
        unsigned short* bc = smem + (r & 1) * 8192;
        if (r + 1 < NROUNDS) ISSUE_TILE(r + 1, smem + ((r + 1) & 1) * 8192);
        const int rbase = r * 128;

        #pragma unroll
        for (int nt = 0; nt < 8; ++nt) {
            const int cl = nt * 16 + n_a;
            const unsigned short* bp = bc + cl * 64;
            half8 b0 = *(const half8*)(bp + ((quad ^ (n_a & 7)) * 8));
            half8 b1 = *(const half8*)(bp + (((4 + quad) ^ (n_a & 7)) * 8));
            const unsigned c = (unsigned)(rbase + nt * 16 + n_a);   // 11-bit local code
            #pragma unroll
            for (int mt = 0; mt < 2; ++mt) {
                f32x4 a = {1.f, 1.f, 1.f, 1.f};   // +1 bias keeps values positive
                a = MFMA_F16(a_h[mt][0], b0, a);
                a = MFMA_F16(a_h[mt][1], b1, a);
                #pragma unroll
                for (int i = 0; i < 4; ++i) {
                    float pk = __uint_as_float((__float_as_uint(a[i]) & 0xFFFFF800u) | c);
                    m2v[mt][i] = __builtin_amdgcn_fmed3f(pk, m1v[mt][i], m2v[mt][i]);
                    m1v[mt][i] = fmaxf(m1v[mt][i], pk);
                }
            }
        }
        __syncthreads();
    }

    #pragma unroll
    for (int mt = 0; mt < 2; ++mt)
        #pragma unroll
        for (int i = 0; i < 4; ++i) {
            float v1 = m1v[mt][i], v2 = m2v[mt][i];
            #pragma unroll
            for (int off = 1; off < 16; off <<= 1) {
                float o1 = __shfl_xor(v1, off);
                float o2 = __shfl_xor(v2, off);
                float lo = fminf(v1, o1);
                v2 = fmaxf(fmaxf(v2, o2), lo);
                v1 = fmaxf(v1, o1);
            }
            if (n_a == 0) {
                int row_g = rowblk * 128 + wv * 32 + mt * 16 + quad * 4 + i;
                pm1[row_g * 4 + kq] = v1;
                pack[row_g * 4 + kq] = __float_as_uint(v2);
            }
        }
    #undef ISSUE_TILE
}

// ---------------- kernel C: merge 4 K-partials; flag rows; emit per-partition candidate lists ----------------
__global__ void merge_kernel(const float* __restrict__ pm1, const unsigned int* __restrict__ pack,
                             int* __restrict__ idx_ws,
                             int* __restrict__ countk, unsigned int* __restrict__ lists) {
    int row = blockIdx.x * blockDim.x + threadIdx.x;
    if (row >= N_ROWS) return;
    float a1[KSPLIT];
    float v1 = -3.4e38f, v2 = -3.4e38f;
    int bq = 0;
    #pragma unroll
    for (int kq = 0; kq < KSPLIT; ++kq) {
        a1[kq] = pm1[row * 4 + kq];
        float a2 = __uint_as_float(pack[row * 4 + kq]);
        if (a1[kq] > v1) { v2 = fmaxf(v1, a2); v1 = a1[kq]; bq = kq; }
        else { v2 = fmaxf(v2, a1[kq]); }
    }
    idx_ws[row] = (int)(__float_as_uint(v1) & 0x7FFu) + bq * KPER;
    float vt1 = __uint_as_float(__float_as_uint(v1) & 0xFFFFF800u);
    float vt2 = __uint_as_float(__float_as_uint(v2) & 0xFFFFF800u);
    if (vt1 - vt2 < MARGIN) {
        #pragma unroll
        for (int kq = 0; kq < KSPLIT; ++kq) {
            float at1 = __uint_as_float(__float_as_uint(a1[kq]) & 0xFFFFF800u);
            if (at1 >= vt1 - MARGIN) {        // partition can contain the fp32 winner
                int pos = atomicAdd(&countk[kq], 1);
                if (pos < LIST_CAP) lists[kq * LIST_CAP + pos] = (unsigned)row;
            }
        }
    }
}

// ---------------- kernel D: exact fp32 re-rank over surviving partitions only ----------------
// unit = (kq, group of 16 rows from list_kq, chunk of 1024 codes). Result per row via
// atomicMin on fbcell[row] with u64 (ordered(dist) << 13 | code): min == lowest dist, then lowest code.
__launch_bounds__(256, 4)
__global__ void fallback_kernel(const float* __restrict__ zn, const float* __restrict__ wT,
                                const float* __restrict__ wsq,
                                const int* __restrict__ countk, const unsigned int* __restrict__ lists,
                                unsigned long long* __restrict__ fbcell) {
    __shared__ float zr_s[FB_ROWS][64];
    __shared__ unsigned long long red_s[FB_ROWS][4];

    const int t = threadIdx.x;
    const int lane = t & 63;
    const int wv = t >> 6;

    int cnt[4], ng[4];
    #pragma unroll
    for (int q = 0; q < 4; ++q) {
        cnt[q] = min(countk[q], LIST_CAP);
        ng[q] = (cnt[q] + FB_ROWS - 1) / FB_ROWS;
    }
    const int t0 = 2 * ng[0], t1 = t0 + 2 * ng[1], t2 = t1 + 2 * ng[2], t3 = t2 + 2 * ng[3];

    for (int bi = blockIdx.x; bi < t3; bi += gridDim.x) {
        int kq, r;
        if (bi < t0)      { kq = 0; r = bi; }
        else if (bi < t1) { kq = 1; r = bi - t0; }
        else if (bi < t2) { kq = 2; r = bi - t1; }
        else              { kq = 3; r = bi - t2; }
        const int g = r >> 1;
        const int chunk = r & 1;
        const unsigned int* lst = lists + kq * LIST_CAP;
        const int count = cnt[kq];

        __syncthreads();   // protect LDS reuse across grid-stride iterations
        for (int i = t; i < FB_ROWS * 64; i += 256) {
            int rl = i >> 6, d = i & 63;
            int slot = g * FB_ROWS + rl;
            int row = (int)lst[slot < count ? slot : (count - 1)];
            zr_s[rl][d] = zn[(size_t)row * DIM + d];
        }
        __syncthreads();

        const int c0 = kq * KPER + chunk * 1024 + t;
        float acc[4][FB_ROWS];
        #pragma unroll
        for (int j = 0; j < 4; ++j)
            #pragma unroll
            for (int rr = 0; rr < FB_ROWS; ++rr) acc[j][rr] = 0.f;

        const float* wTp = wT + c0;
        #pragma unroll 2
        for (int d = 0; d < 64; ++d) {
            const float* p = wTp + (size_t)d * KCODES;
            float w0 = p[0], w1 = p[256], w2 = p[512], w3 = p[768];
            #pragma unroll
            for (int rr = 0; rr < FB_ROWS; ++rr) {
                float zd = zr_s[rr][d];
                acc[0][rr] = fmaf(zd, w0, acc[0][rr]);
                acc[1][rr] = fmaf(zd, w1, acc[1][rr]);
                acc[2][rr] = fmaf(zd, w2, acc[2][rr]);
                acc[3][rr] = fmaf(zd, w3, acc[3][rr]);
            }
        }
        float q0 = wsq[c0], q1 = wsq[c0 + 256], q2 = wsq[c0 + 512], q3 = wsq[c0 + 768];

        #pragma unroll
        for (int rr = 0; rr < FB_ROWS; ++rr) {
            float dj[4] = {q0 - 2.f * acc[0][rr], q1 - 2.f * acc[1][rr],
                           q2 - 2.f * acc[2][rr], q3 - 2.f * acc[3][rr]};
            unsigned long long best = 0xFFFFFFFFFFFFFFFFull;
            #pragma unroll
            for (int j = 0; j < 4; ++j) {
                int s = __float_as_int(dj[j]);
                unsigned o = (unsigned)s ^ (unsigned)((s >> 31) | (int)0x80000000);
                unsigned long long pk = ((unsigned long long)o << 13) | (unsigned)(c0 + j * 256);
                best = pk < best ? pk : best;
            }
            #pragma unroll
            for (int off = 1; off < 64; off <<= 1) {
                unsigned lo = __shfl_xor((unsigned)(best & 0xffffffffu), off);
                unsigned hi = __shfl_xor((unsigned)(best >> 32), off);
                unsigned long long ob = ((unsigned long long)hi << 32) | lo;
                best = ob < best ? ob : best;
            }
            if (lane == 0) red_s[rr][wv] = best;
        }
        __syncthreads();
        if (t < FB_ROWS) {
            unsigned long long best = red_s[t][0];
            #pragma unroll
            for (int i2 = 1; i2 < 4; ++i2) best = red_s[t][i2] < best ? red_s[t][i2] : best;
            int slot = g * FB_ROWS + t;
            if (slot < count) atomicMin(&fbcell[lst[slot]], best);
        }
    }
}

// ---------------- kernel D2: resolve flagged rows from fbcell + zero esum for the scatter ----------------
__global__ void merge2_kernel(const unsigned long long* __restrict__ fbcell,
                              int* __restrict__ idx_ws, float* __restrict__ esum) {
    int gid = blockIdx.x * blockDim.x + threadIdx.x;   // grid 256x256 = 65536
    unsigned long long v = fbcell[gid];
    if (v != 0xFFFFFFFFFFFFFFFFull) idx_ws[gid] = (int)(v & 0x1FFFull);
    float4 zz = {0.f, 0.f, 0.f, 0.f};
    ((float4*)esum)[gid * 2] = zz;
    ((float4*)esum)[gid * 2 + 1] = zz;
}

// ---------------- kernel E: gather z_q (over zn in-place), idx out, loss, EMA scatter ----------------
__global__ void stats_kernel(float* __restrict__ zq,              // holds zn on entry
                             const float* __restrict__ w,
                             const int* __restrict__ idx_ws,
                             float* __restrict__ idx_out,
                             float* __restrict__ bins,
                             float* __restrict__ esum,
                             float* __restrict__ loss_acc) {
    const int lane = threadIdx.x & 63;
    const int wv = threadIdx.x >> 6;
    const int gw = blockIdx.x * 4 + wv;
    const int nw = gridDim.x * 4;
    float lsum = 0.f;
    for (int row = gw; row < N_ROWS; row += nw) {
        float znv = zq[(size_t)row * DIM + lane];
        int k = idx_ws[row];
        float wq = w[(size_t)k * DIM + lane];
        zq[(size_t)row * DIM + lane] = wq;
        if (lane == 0) idx_out[row] = (float)k;
        float diff = wq - znv;
        lsum += diff * diff;
        atomicAdd(&esum[(size_t)k * DIM + lane], znv);
        if (lane == 0) atomicAdd(&bins[k], 1.0f);
    }
    __shared__ float red[256];
    red[threadIdx.x] = lsum;
    __syncthreads();
    for (int s = 128; s > 0; s >>= 1) {
        if (threadIdx.x < s) red[threadIdx.x] += red[threadIdx.x + s];
        __syncthreads();
    }
    if (threadIdx.x == 0) atomicAdd(loss_acc, red[0]);
}

// ---------------- kernel F: per-code EMA finalize + loss scalar ----------------
__global__ void finalize_kernel(const float* __restrict__ w,
                                const float* __restrict__ cs,
                                const float* __restrict__ ea,
                                const float* __restrict__ bins,
                                const float* __restrict__ esum,
                                const float* __restrict__ loss_acc,
                                float* __restrict__ out_cs,
                                float* __restrict__ out_ea,
                                float* __restrict__ out_w,
                                float* __restrict__ out_loss) {
    const int gid = blockIdx.x * blockDim.x + threadIdx.x;
    if (gid == 0) out_loss[0] = 0.25f * loss_acc[0] / 4194304.0f;
    const int k = gid >> 6;
    const int lane = threadIdx.x & 63;
    if (k >= KCODES) return;
    float b = bins[k];
    if (lane == 0) out_cs[k] = cs[k] * 0.99f + 0.01f * b;
    size_t off = (size_t)k * DIM + lane;
    float es = esum[off];
    out_ea[off] = ea[off] * 0.99f + 0.01f * es;
    float wv = w[off];
    float bc = (b == 0.0f) ? 1.0f : b;
    float t = es / bc;
    float s = t * t;
    #pragma unroll
    for (int o = 32; o > 0; o >>= 1) s += __shfl_xor(s, o);
    float en = t / fmaxf(sqrtf(s), 1e-12f);
    if (b == 0.0f) en = wv;
    float nw = wv * 0.99f + 0.01f * en;
    float s2 = nw * nw;
    #pragma unroll
    for (int o = 32; o > 0; o >>= 1) s2 += __shfl_xor(s2, o);
    out_w[off] = nw / fmaxf(sqrtf(s2), 1e-12f);
}

extern "C" void kernel_launch(void* const* d_in, const int* in_sizes, int n_in,
                              void* d_out, int out_size, void* d_ws, size_t ws_size,
                              hipStream_t stream) {
    const float* z  = (const float*)d_in[0];
    const float* w  = (const float*)d_in[1];
    const float* cs = (const float*)d_in[2];
    const float* ea = (const float*)d_in[3];

    float* out = (float*)d_out;
    float* out_zq   = out;                 // 4194304  (zn scratch)
    float* out_loss = out + 4194304;       // 1
    float* out_idx  = out + 4194305;       // 65536    (lists scratch)
    float* out_cs   = out + 4259841;       // 8192     (countk scratch)
    float* out_ea   = out + 4268033;       // 524288   (wh + fbcell scratch)
    float* out_w    = out + 4792321;       // 524288   (pm1 + pack scratch)

    float*              zn     = out_zq;
    unsigned int*       lists  = (unsigned int*)(out + 4194305);     // 4 x 16384
    int*                countk = (int*)(out + 4259841);              // 4 ints
    unsigned short*     wh     = (unsigned short*)(out + 4268032);   // 16B-aligned, 1MB
    unsigned long long* fbcell = (unsigned long long*)(out + 4530178); // 8B-aligned, 512KB
    float*              pm1    = out + 4792321;
    unsigned int*       pack   = (unsigned int*)(out + 5054465);

    float* ws = (float*)d_ws;
    float* wsq  = ws + WS_WSQ;
    int*   idxb = (int*)(ws + WS_IDX);
    float* bins = ws + WS_BINS;
    float* esum = ws + WS_ESUM;
    float* wT   = ws + WS_ESUM;            // wT lives here until merge2 zeroes esum
    float* loss = ws + WS_LOSS;

    prep_kernel<<<NZB + NWB + NTB, 256, 0, stream>>>(z, w, zn, wsq, wh, wT, bins, countk,
                                                     fbcell, loss);
    argmin_mfma_kernel<<<(N_ROWS / 128) * KSPLIT, 256, 0, stream>>>(zn, wh, pm1, pack);
    merge_kernel<<<N_ROWS / 256, 256, 0, stream>>>(pm1, pack, idxb, countk, lists);
    fallback_kernel<<<1024, 256, 0, stream>>>(zn, wT, wsq, countk, lists, fbcell);
    merge2_kernel<<<N_ROWS / 256, 256, 0, stream>>>(fbcell, idxb, esum);
    stats_kernel<<<512, 256, 0, stream>>>(out_zq, w, idxb, out_idx, bins, esum, loss);
    finalize_kernel<<<KCODES * 64 / 256, 256, 0, stream>>>(w, cs, ea, bins, esum, loss,
                                                           out_cs, out_ea, out_w, out_loss);
}